// Round 26
// baseline (134.798 us; speedup 1.0000x reference)
//
#include <hip/hip_runtime.h>
#include <hip/hip_bf16.h>
#include <math.h>

// B=2, S=2048, D=1024, H=16, dk=64.   3 dispatches, no weight pre-pass:
// tri-GEMM (A fp32 + W fp32 both reg-staged -> fp16 LDS in-register; A RTZ
// cvtpk16 / W RNE scalar casts (bit-matches deleted wsplit); 1-term fp16 MFMA;
// single barrier/iter — pure reg staging, no gload queue to preserve)
// -> 32x32-MFMA flash attention (r22/r25 structure, fp16 RNE X epilogue)
// -> 1-term fp16 GEMM0 (X u16x8 reg-copied, Wo fp32 reg-converted RNE).
//
// GEMM LDS/buf (16KB x2 = 32KB): A/X f16 8KB | W f16 8KB, [128][32] swz layout.
// Tiled K per (b,h): tile t at t*4096; elem(key r, dk d) = chunk(d>>3)*512+r*8+(d&7).
// Tiled V per (b,h): tile t at t*4096; elem(dk d, key s) = chunk((s&63)>>3)*512+d*8+(s&7).
//
// ws (64 MB): [0,8) Xh fp16 | [16,24) qb | [24,32) vt | [40,48) kb.

#define B_ 2
#define S_ 2048
#define D_ 1024
#define H_ 16
#define DK 64

typedef __attribute__((ext_vector_type(8)))  __bf16    bf16x8;
typedef __attribute__((ext_vector_type(8)))  _Float16  f16x8;
typedef __attribute__((ext_vector_type(4)))  float     f32x4;
typedef __attribute__((ext_vector_type(16))) float     f32x16;
typedef __attribute__((ext_vector_type(8)))  unsigned short u16x8;
typedef __attribute__((ext_vector_type(4)))  unsigned short u16x4;

#if __has_builtin(__builtin_amdgcn_exp2f)
#define EXP2(x) __builtin_amdgcn_exp2f(x)
#else
#define EXP2(x) exp2f(x)
#endif

static __device__ __forceinline__ unsigned short f2bf(float x) {
    union { float f; unsigned u; } v; v.f = x;
    unsigned r = v.u + 0x7FFFu + ((v.u >> 16) & 1u);   // RNE
    return (unsigned short)(r >> 16);
}
static __device__ __forceinline__ unsigned cvtpk(float lo, float hi) {
    unsigned r;
    asm("v_cvt_pk_bf16_f32 %0, %1, %2" : "=v"(r) : "v"(lo), "v"(hi));
    return r;
}
static __device__ __forceinline__ unsigned cvtpk16(float lo, float hi) {
    unsigned r;
    asm("v_cvt_pkrtz_f16_f32 %0, %1, %2" : "=v"(r) : "v"(lo), "v"(hi));
    return r;
}
static __device__ __forceinline__ void gload_lds16(const void* g, void* l) {
    __builtin_amdgcn_global_load_lds(
        (const __attribute__((address_space(1))) void*)g,
        (__attribute__((address_space(3))) void*)l, 16, 0, 0);
}
static __device__ __forceinline__ int swz(int R, int c) {
    return ((R >> 1) << 6) + (((((R & 1) << 2) | c) ^ ((R >> 1) & 7)) << 3);
}
// A pack: 8 fp32 -> u16x8 fp16 RTZ (cvtpk), matches verified trigemm path.
static __device__ __forceinline__ u16x8 packA(float4 a, float4 b) {
    union { unsigned u[4]; u16x8 v; } hh;
    hh.u[0] = cvtpk16(a.x, a.y); hh.u[1] = cvtpk16(a.z, a.w);
    hh.u[2] = cvtpk16(b.x, b.y); hh.u[3] = cvtpk16(b.z, b.w);
    return hh.v;
}
// W pack: 8 fp32 -> u16x8 fp16 RNE (scalar casts), bit-matches deleted wsplit.
static __device__ __forceinline__ u16x8 packW(float4 a, float4 b) {
    union { _Float16 h[8]; u16x8 v; } hh;
    hh.h[0]=(_Float16)a.x; hh.h[1]=(_Float16)a.y;
    hh.h[2]=(_Float16)a.z; hh.h[3]=(_Float16)a.w;
    hh.h[4]=(_Float16)b.x; hh.h[5]=(_Float16)b.y;
    hh.h[6]=(_Float16)b.z; hh.h[7]=(_Float16)b.w;
    return hh.v;
}

// ---------------------------------------------------------------------------
// Fused tri-GEMM: A fp32 + W fp32 reg-staged -> fp16 LDS; 1-term fp16 MFMA;
// single barrier per K-step (pure reg staging). Epilogues unchanged.
// ---------------------------------------------------------------------------
__global__ __launch_bounds__(512) void trigemm(
    const float* __restrict__ Aq, const float* __restrict__ Ak,
    const float* __restrict__ Av,
    const float* __restrict__ Wq, const float* __restrict__ Wk,
    const float* __restrict__ Wv,
    const float* __restrict__ bq, const float* __restrict__ bk,
    const float* __restrict__ bv,
    unsigned short* __restrict__ qb, unsigned short* __restrict__ kb,
    unsigned short* __restrict__ vt)
{
    __shared__ __align__(16) char ldsb[32768];   // 2 bufs x (A16 8K | W16 8K)
    const int pid = blockIdx.z;
    const float* A    = (pid==0) ? Aq : (pid==1) ? Ak : Av;
    const float* W    = (pid==0) ? Wq : (pid==1) ? Wk : Wv;
    const float* bias = (pid==0) ? bq : (pid==1) ? bk : bv;

    const int tid = threadIdx.x;
    const int w = tid >> 6, lane = tid & 63;
    const int l15 = lane & 15, g4 = lane >> 4;
    const int wr = w >> 1, wc = w & 1;
    const int bx = blockIdx.x, by = blockIdx.y;

    // staging: thread -> row tid>>2, 8-elem chunk tid&3 (same map for A and W)
    const int arow = tid >> 2, ac = tid & 3;
    const float* gpA = A + (size_t)(bx*128 + arow) * 1024 + ac * 8;
    const float* gpW = W + (size_t)(by*128 + arow) * 1024 + ac * 8;
    const int aoff = swz(arow, ac);          // A half [0,4096) shorts
    const int woff = 4096 + aoff;            // W half

    f32x4 acc[2][4];
    #pragma unroll
    for (int m = 0; m < 2; ++m)
        #pragma unroll
        for (int n = 0; n < 4; ++n) acc[m][n] = (f32x4){0.f,0.f,0.f,0.f};

    // ---- prologue: tile 0 ----
    {
        float4 a0 = *(const float4*)(gpA);
        float4 a1 = *(const float4*)(gpA + 4);
        float4 w0 = *(const float4*)(gpW);
        float4 w1 = *(const float4*)(gpW + 4);
        *(u16x8*)((unsigned short*)ldsb + aoff) = packA(a0, a1);
        *(u16x8*)((unsigned short*)ldsb + woff) = packW(w0, w1);
    }
    asm volatile("s_waitcnt lgkmcnt(0)" ::: "memory");
    __builtin_amdgcn_s_barrier();
    asm volatile("" ::: "memory");

    for (int t = 0; t < 32; ++t) {
        const int cur = t & 1;
        float4 na0, na1, nw0, nw1;
        if (t < 31) {                         // issue next-tile loads early
            na0 = *(const float4*)(gpA + (size_t)(t+1)*32);
            na1 = *(const float4*)(gpA + (size_t)(t+1)*32 + 4);
            nw0 = *(const float4*)(gpW + (size_t)(t+1)*32);
            nw1 = *(const float4*)(gpW + (size_t)(t+1)*32 + 4);
        }

        const unsigned short* Ab = (const unsigned short*)(ldsb + cur*16384);
        const unsigned short* Wb = Ab + 4096;
        f16x8 ah[2], wh4[4];
        #pragma unroll
        for (int m = 0; m < 2; ++m)
            ah[m] = *(const f16x8*)(Ab + swz(wr*32 + m*16 + l15, g4));
        #pragma unroll
        for (int n = 0; n < 4; ++n)
            wh4[n] = *(const f16x8*)(Wb + swz(wc*64 + n*16 + l15, g4));
        #pragma unroll
        for (int m = 0; m < 2; ++m)
            #pragma unroll
            for (int n = 0; n < 4; ++n)
                acc[m][n] = __builtin_amdgcn_mfma_f32_16x16x32_f16(ah[m], wh4[n], acc[m][n], 0,0,0);

        if (t < 31) {                         // convert + write next tile
            unsigned short* nb = (unsigned short*)(ldsb + (cur^1)*16384);
            *(u16x8*)(nb + aoff) = packA(na0, na1);
            *(u16x8*)(nb + woff) = packW(nw0, nw1);
        }
        asm volatile("s_waitcnt lgkmcnt(0)" ::: "memory");   // writes visible
        __builtin_amdgcn_s_barrier();                        // reads+writes done
        asm volatile("" ::: "memory");
    }

    const int colBase = by*128 + wc*64;
    const int rowBase = bx*128 + wr*32;
    const int h = colBase >> 6;

    if (pid < 2) {
        unsigned short* Out = pid ? kb : qb;
        const float QSC = pid ? 1.0f : 0.125f * 1.44269504088896340736f;
        #pragma unroll
        for (int m = 0; m < 2; ++m) {
            const int srow0 = rowBase + m*16 + g4*4;
            const int b = srow0 >> 11;
            unsigned short* hb2 = Out + (size_t)(b*H_ + h) * S_ * DK;
            #pragma unroll
            for (int n = 0; n < 2; ++n) {
                const int d = n*16 + l15;
                const float invf = exp2f((float)d * -0.4152410118609203f);
                const float b1 = bias[h*64 + d], b2 = bias[h*64 + d + 32];
                #pragma unroll
                for (int r = 0; r < 4; ++r) {
                    const int s = (srow0 + r) & 2047;
                    const float x1 = acc[m][n][r]   + b1;
                    const float x2 = acc[m][n+2][r] + b2;
                    float sn, cc;
                    __sincosf((float)s * invf, &sn, &cc);
                    const float o1 = (x1*cc - x2*sn) * QSC;
                    const float o2 = (x2*cc + x1*sn) * QSC;
                    if (pid == 0) {
                        unsigned short* dst = hb2 + (size_t)s * DK;
                        dst[d]      = f2bf(o1);
                        dst[d + 32] = f2bf(o2);
                    } else {
                        unsigned short* tb = hb2 + (s >> 6) * 4096 + (s & 63) * 8;
                        tb[(d >> 3) * 512 + (d & 7)]        = f2bf(o1);
                        tb[(d >> 3) * 512 + 2048 + (d & 7)] = f2bf(o2);
                    }
                }
            }
        }
    } else {
        #pragma unroll
        for (int m = 0; m < 2; ++m) {
            const int srow0 = rowBase + m*16 + g4*4;
            const int b = srow0 >> 11, s0 = srow0 & 2047;
            unsigned short* tb = vt + (size_t)(b*H_ + h) * S_ * DK
                               + (s0 >> 6) * 4096 + ((s0 & 63) >> 3) * 512 + (s0 & 7);
            #pragma unroll
            for (int n = 0; n < 4; ++n) {
                const int d = n*16 + l15;
                const float bb = bias[h*64 + d];
                u16x4 pk;
                #pragma unroll
                for (int r = 0; r < 4; ++r) pk[r] = f2bf(acc[m][n][r] + bb);
                *(u16x4*)(tb + d * 8) = pk;
            }
        }
    }
}

// ---------------------------------------------------------------------------
// 32x32-MFMA flash attention (r22/r25 structure), fp16 RNE X epilogue.
// ---------------------------------------------------------------------------
__global__ __launch_bounds__(512, 1) void attn_mfma8(
    const unsigned short* __restrict__ Qb, const unsigned short* __restrict__ Kb,
    const unsigned short* __restrict__ Vt, unsigned short* __restrict__ Xh)
{
    __shared__ __align__(16) char lds[65536];
    const unsigned bid = blockIdx.x;
    const int xcd = bid & 7, idx = bid >> 3;
    const int bh  = xcd * 4 + (idx >> 3);
    const int qt  = idx & 7;
    const int tid = threadIdx.x;
    const int w = tid >> 6, lane = tid & 63;
    const int l31 = lane & 31, hi = lane >> 5;
    const size_t bhO = (size_t)bh * S_ * DK;
    const int q0 = qt * 256 + w * 32;

    const int u0   = w * 4;
    const int isV  = u0 >> 4;
    const int u15  = u0 & 15;
    const int su0  = u15 >> 3;
    const unsigned short* sb = (isV ? Vt : Kb) + bhO;
    const int ch0 = u15 & 7;
    char* const dbase = lds;

    bf16x8 qf[4];
    #pragma unroll
    for (int ks = 0; ks < 4; ++ks)
        qf[ks] = *(const bf16x8*)(Qb + bhO + (size_t)(q0 + l31) * DK + ks*16 + hi*8);

    f32x16 oT[2];
    #pragma unroll
    for (int dh = 0; dh < 2; ++dh)
        #pragma unroll
        for (int r = 0; r < 16; ++r) oT[dh][r] = 0.f;
    float l_ = 0.f;

    #define ASTAGE(T, BUF) do {                                                     \
        const unsigned short* g_ = sb + (size_t)((T)*2 + su0) * 4096 + ch0 * 512    \
                                   + lane * 8;                                      \
        char* d_ = dbase + (BUF)*32768 + isV*16384 + su0*8192 + ch0*1024 + lane*16; \
        gload_lds16(g_,         d_);                                                \
        gload_lds16(g_ + 512,   d_ + 1024);                                         \
        gload_lds16(g_ + 1024,  d_ + 2048);                                         \
        gload_lds16(g_ + 1536,  d_ + 3072);                                         \
    } while (0)

    ASTAGE(0, 0);
    asm volatile("s_waitcnt vmcnt(0)" ::: "memory");
    __builtin_amdgcn_s_barrier();
    asm volatile("" ::: "memory");

    for (int t = 0; t < 16; ++t) {
        const int cur = t & 1;
        if (t < 15) {
            ASTAGE(t + 1, cur ^ 1);
            asm volatile("s_waitcnt vmcnt(4)" ::: "memory");
        } else {
            asm volatile("s_waitcnt vmcnt(0)" ::: "memory");
        }
        __builtin_amdgcn_s_barrier();
        asm volatile("" ::: "memory");

        const char* Kl = lds + cur * 32768;
        const char* Vl = Kl + 16384;

        f32x16 s2[4];
        __builtin_amdgcn_s_setprio(1);
        #pragma unroll
        for (int kb2 = 0; kb2 < 4; ++kb2) {
            f32x16 a;
            #pragma unroll
            for (int r = 0; r < 16; ++r) a[r] = 0.f;
            const char* kbase = Kl + (kb2 >> 1) * 8192 + ((kb2 & 1) * 32 + l31) * 16;
            #pragma unroll
            for (int ks = 0; ks < 4; ++ks) {
                bf16x8 kf = *(const bf16x8*)(kbase + (ks*2 + hi) * 1024);
                a = __builtin_amdgcn_mfma_f32_32x32x16_bf16(kf, qf[ks], a, 0, 0, 0);
            }
            s2[kb2] = a;
        }
        __builtin_amdgcn_s_setprio(0);

        {
            float lsum = 0.f;
            #pragma unroll
            for (int kb2 = 0; kb2 < 4; ++kb2)
                #pragma unroll
                for (int r = 0; r < 16; ++r) {
                    const float p = EXP2(s2[kb2][r]);
                    s2[kb2][r] = p; lsum += p;
                }
            l_ += lsum;
        }

        #pragma unroll
        for (int ks2 = 0; ks2 < 8; ++ks2) {
            const int kb2 = ks2 >> 1;
            const int R0  = (ks2 & 1) * 8;
            unsigned a0 = cvtpk(s2[kb2][R0+0], s2[kb2][R0+1]);
            unsigned a1 = cvtpk(s2[kb2][R0+2], s2[kb2][R0+3]);
            unsigned b0 = cvtpk(s2[kb2][R0+4], s2[kb2][R0+5]);
            unsigned b1 = cvtpk(s2[kb2][R0+6], s2[kb2][R0+7]);
            asm("v_permlane32_swap_b32 %0, %1" : "+v"(a0), "+v"(b0));
            asm("v_permlane32_swap_b32 %0, %1" : "+v"(a1), "+v"(b1));
            union { unsigned u[4]; bf16x8 v; } pf;
            pf.u[0] = a0; pf.u[1] = a1; pf.u[2] = b0; pf.u[3] = b1;
            const char* vbase = Vl + (ks2 >> 2) * 8192 + (((ks2 & 3) * 2) + hi) * 1024;
            __builtin_amdgcn_s_setprio(1);
            #pragma unroll
            for (int dh = 0; dh < 2; ++dh) {
                bf16x8 vf = *(const bf16x8*)(vbase + (dh*32 + l31) * 16);
                oT[dh] = __builtin_amdgcn_mfma_f32_32x32x16_bf16(vf, pf.v, oT[dh], 0, 0, 0);
            }
            __builtin_amdgcn_s_setprio(0);
        }

        asm volatile("" ::: "memory");
        __builtin_amdgcn_s_barrier();
        asm volatile("" ::: "memory");
    }
    #undef ASTAGE

    l_ += __shfl_xor(l_, 32, 64);
    const float inv = 1.0f / l_;
    const int b = bh >> 4, h = bh & 15;
    const int q = q0 + l31;
    unsigned short* xh = Xh + (((size_t)b * S_ + q) * H_ + h) * DK;
    #pragma unroll
    for (int dh = 0; dh < 2; ++dh)
        #pragma unroll
        for (int tt = 0; tt < 4; ++tt) {
            const int dk0 = dh*32 + tt*8 + hi*4;
            union { _Float16 hh[4]; u16x4 v; } o;
            #pragma unroll
            for (int r = 0; r < 4; ++r)
                o.hh[r] = (_Float16)(oT[dh][tt*4 + r] * inv);   // RNE
            *(u16x4*)(xh + dk0) = o.v;
        }
}

// ---------------------------------------------------------------------------
// Output projection: 1-term fp16 GEMM. X u16x8 reg-copied; Wo fp32 reg-
// converted (RNE). Single barrier per K-step.
// ---------------------------------------------------------------------------
__global__ __launch_bounds__(512) void mfma_gemm0(
    const unsigned short* __restrict__ Xh, const float* __restrict__ Wo,
    const float* __restrict__ bias, float* __restrict__ Out)
{
    __shared__ __align__(16) char ldsb[32768];   // 2 bufs x (X16 8K | W16 8K)
    const int tid = threadIdx.x;
    const int w = tid >> 6, lane = tid & 63;
    const int l15 = lane & 15, g4 = lane >> 4;
    const int wr = w >> 1, wc = w & 1;
    const int bx = blockIdx.x, by = blockIdx.y;

    const int arow = tid >> 2, ac = tid & 3;
    const unsigned short* gpX = Xh + (size_t)(bx*128 + arow) * 1024 + ac * 8;
    const float*          gpW = Wo + (size_t)(by*128 + arow) * 1024 + ac * 8;
    const int aoff = swz(arow, ac);
    const int woff = 4096 + aoff;

    f32x4 acc[2][4];
    #pragma unroll
    for (int m = 0; m < 2; ++m)
        #pragma unroll
        for (int n = 0; n < 4; ++n) acc[m][n] = (f32x4){0.f,0.f,0.f,0.f};

    {
        u16x8  x0 = *(const u16x8*)(gpX);
        float4 w0 = *(const float4*)(gpW);
        float4 w1 = *(const float4*)(gpW + 4);
        *(u16x8*)((unsigned short*)ldsb + aoff) = x0;
        *(u16x8*)((unsigned short*)ldsb + woff) = packW(w0, w1);
    }
    asm volatile("s_waitcnt lgkmcnt(0)" ::: "memory");
    __builtin_amdgcn_s_barrier();
    asm volatile("" ::: "memory");

    for (int t = 0; t < 32; ++t) {
        const int cur = t & 1;
        u16x8  nx0;
        float4 nw0, nw1;
        if (t < 31) {
            nx0 = *(const u16x8*)(gpX + (size_t)(t+1)*32);
            nw0 = *(const float4*)(gpW + (size_t)(t+1)*32);
            nw1 = *(const float4*)(gpW + (size_t)(t+1)*32 + 4);
        }

        const unsigned short* Ab = (const unsigned short*)(ldsb + cur*16384);
        const unsigned short* Wb = Ab + 4096;
        f16x8 ah2[2], wh4[4];
        #pragma unroll
        for (int m = 0; m < 2; ++m)
            ah2[m] = *(const f16x8*)(Ab + swz(wr*32 + m*16 + l15, g4));
        #pragma unroll
        for (int n = 0; n < 4; ++n)
            wh4[n] = *(const f16x8*)(Wb + swz(wc*64 + n*16 + l15, g4));
        #pragma unroll
        for (int m = 0; m < 2; ++m)
            #pragma unroll
            for (int n = 0; n < 4; ++n)
                acc[m][n] = __builtin_amdgcn_mfma_f32_16x16x32_f16(ah2[m], wh4[n], acc[m][n], 0,0,0);

        if (t < 31) {
            unsigned short* nb = (unsigned short*)(ldsb + (cur^1)*16384);
            *(u16x8*)(nb + aoff) = nx0;
            *(u16x8*)(nb + woff) = packW(nw0, nw1);
        }
        asm volatile("s_waitcnt lgkmcnt(0)" ::: "memory");
        __builtin_amdgcn_s_barrier();
        asm volatile("" ::: "memory");
    }

    const int colBase = by*128 + wc*64;
    const int rowBase = bx*128 + wr*32;
    #pragma unroll
    for (int m = 0; m < 2; ++m) {
        const int row = rowBase + m*16 + g4*4;
        #pragma unroll
        for (int n = 0; n < 4; ++n) {
            const int col = colBase + n*16 + l15;
            const float bb = bias[col];
            #pragma unroll
            for (int r = 0; r < 4; ++r)
                Out[(size_t)(row + r) * 1024 + col] = acc[m][n][r] + bb;
        }
    }
}

// ---------------------------------------------------------------------------
extern "C" void kernel_launch(void* const* d_in, const int* in_sizes, int n_in,
                              void* d_out, int out_size, void* d_ws, size_t ws_size,
                              hipStream_t stream)
{
    const float* query = (const float*)d_in[0];
    const float* key   = (const float*)d_in[1];
    const float* value = (const float*)d_in[2];
    const float* Wq = (const float*)d_in[3];  const float* bq = (const float*)d_in[4];
    const float* Wk = (const float*)d_in[5];  const float* bk = (const float*)d_in[6];
    const float* Wv = (const float*)d_in[7];  const float* bv = (const float*)d_in[8];
    const float* Wo = (const float*)d_in[9];  const float* bo = (const float*)d_in[10];
    float* out = (float*)d_out;

    char* ws = (char*)d_ws;
    const size_t MB = (size_t)1 << 20;
    unsigned short* Xh  = (unsigned short*)(ws + 0*MB);
    unsigned short* qb  = (unsigned short*)(ws + 16*MB);
    unsigned short* vt  = (unsigned short*)(ws + 24*MB);
    unsigned short* kb  = (unsigned short*)(ws + 40*MB);

    trigemm<<<dim3(32, 8, 3), 512, 0, stream>>>(query, key, value, Wq, Wk, Wv,
                                                bq, bk, bv, qb, kb, vt);

    attn_mfma8<<<256, 512, 0, stream>>>(qb, kb, vt, Xh);

    mfma_gemm0<<<dim3(32, 8), 512, 0, stream>>>(Xh, Wo, bo, out);
}